// Round 9
// baseline (29232.532 us; speedup 1.0000x reference)
//
#include <hip/hip_runtime.h>
#include <hip/hip_bf16.h>

typedef __bf16 bf16;
typedef __bf16 bf16x8 __attribute__((ext_vector_type(8)));
typedef float  f32x4  __attribute__((ext_vector_type(4)));

#define MFMA16(a,b,c) __builtin_amdgcn_mfma_f32_16x16x32_bf16((a),(b),(c),0,0,0)
#define NSTEP 119
#define BM 16
#define NBLK 256
#define GRP 32

// ws offsets (bf16 elements); frag block (c,kt) = 1024 bf16: [hi 512][lo 512]
#define O_Z2H   0u
#define O_WIH0  196608u
#define O_WHH0  294912u
#define O_WIH1  688128u
#define O_WHH1  1081344u
#define O_WIH2  1474560u
#define O_WHH2  1867776u
#define O_OUTW  2260992u
// barrier words (int indices): after O_OUTW + 32768 bf16 = int index 1146880
#define IBAR_SUB(g) (1146880 + 16 * (g))
#define IBAR_MST    (1146880 + 128)

// A-fragment-major offset for element (row m, col k): lane = m+16*((k>>3)&3), elem k&7
#define FOFF(m,k) (((k)>>5)*512 + ((m) + 16*(((k)>>3)&3))*8 + ((k)&7))

__device__ __forceinline__ f32x4 splat4(float v){ f32x4 r={v,v,v,v}; return r; }

__global__ void bar_init(int* ws_i) {
  int i = threadIdx.x;
  if (i < 160) ws_i[1146880 + i] = 0;
}

// fp32 W[Rt*16][KT*32] row-major -> MFMA B-fragments, hi/lo bf16 split.
__global__ void pack2(const float* __restrict__ src, bf16* __restrict__ dst,
                      int Rt, int KT) {
  int idx = blockIdx.x * 256 + threadIdx.x;
  if (idx >= Rt * KT * 64) return;
  int lane = idx & 63, fi = idx >> 6;
  int r15 = lane & 15, q = lane >> 4;
  int c = fi / KT, kt = fi - c * KT;
  const float* s = src + (size_t)(c * 16 + r15) * (KT * 32) + kt * 32 + q * 8;
  bf16* dhi = dst + (size_t)fi * 1024 + lane * 8;
  bf16* dlo = dhi + 512;
  #pragma unroll
  for (int e = 0; e < 8; ++e) {
    float v = s[e];
    bf16 hi = (bf16)v;
    dhi[e] = hi;
    dlo[e] = (bf16)(v - (float)hi);
  }
}

// Phase barrier: pure cache-phasing (no data crosses blocks; timeout = perf loss
// only, never a hang: every block unconditionally arrives at every barrier).
// Arrivals: two-level RMW (32/line sub + 8 master) to cap contention.
// Release: RELAXED AGENT-scope LOAD poll (no RMW!) -> the sense flip propagates
// as one invalidate + per-XCD L2 refill; block exits disperse in ~1us instead
// of the ~16us RMW-serialized stagger that defeated R8's alignment.
__device__ __forceinline__ void phase_bar(int* __restrict__ wsi, int epoch) {
  __syncthreads();
  if (threadIdx.x == 0) {
    const int g = blockIdx.x & 7;
    int old = atomicAdd(wsi + IBAR_SUB(g), 1);
    if ((old & 0xffff) == GRP - 1) {
      int old2 = atomicAdd(wsi + IBAR_SUB(g), (1 << 16) - GRP);  // reset cnt, bump sub-sense
      int m = atomicAdd(wsi + IBAR_MST, 1 + (int)(old2 >> 31)); // dep on old2 => ordered
      if ((m & 0xffff) == 7)
        atomicAdd(wsi + IBAR_MST, (1 << 16) - 8);               // master sense += 1
    }
    for (int it = 0; it < 2000000; ++it) {
      int v = __hip_atomic_load(wsi + IBAR_MST, __ATOMIC_RELAXED,
                                __HIP_MEMORY_SCOPE_AGENT);
      if ((v >> 16) >= epoch) break;
      __builtin_amdgcn_s_sleep(2);
    }
  }
  __syncthreads();
}

// acc[NT] += A x W^T, 3-pass split MFMA, depth-1 register prefetch of B frags.
template<int KT, int NT>
__device__ __forceinline__ void gemm3f(f32x4* acc,
    const bf16* __restrict__ A0, const bf16* __restrict__ A1,
    const bf16* __restrict__ BF, const int cbase, const int cstep, const int lane)
{
  bf16x8 b0[NT], b1[NT], n0[NT], n1[NT];
  #pragma unroll
  for (int t = 0; t < NT; ++t) {
    const bf16* bp = BF + (size_t)((cbase + t * cstep) * KT) * 1024 + lane * 8;
    b0[t] = *(const bf16x8*)bp;
    b1[t] = *(const bf16x8*)(bp + 512);
  }
  #pragma unroll
  for (int kt = 0; kt < KT; ++kt) {
    if (kt + 1 < KT) {
      #pragma unroll
      for (int t = 0; t < NT; ++t) {
        const bf16* bp = BF + (size_t)((cbase + t * cstep) * KT + kt + 1) * 1024 + lane * 8;
        n0[t] = *(const bf16x8*)bp;
        n1[t] = *(const bf16x8*)(bp + 512);
      }
    }
    bf16x8 a0 = *(const bf16x8*)(A0 + kt * 512 + lane * 8);
    bf16x8 a1 = *(const bf16x8*)(A1 + kt * 512 + lane * 8);
    #pragma unroll
    for (int t = 0; t < NT; ++t) {
      acc[t] = MFMA16(a0, b0[t], acc[t]);
      acc[t] = MFMA16(a1, b0[t], acc[t]);
      acc[t] = MFMA16(a0, b1[t], acc[t]);
    }
    if (kt + 1 < KT) {
      #pragma unroll
      for (int t = 0; t < NT; ++t) { b0[t] = n0[t]; b1[t] = n1[t]; }
    }
  }
}

// GRU gate update for one layer; h comps 0/1 in LDS (frag-major), comp2 in regs.
__device__ __forceinline__ void upd(bf16* __restrict__ hc0, bf16* __restrict__ hc1,
    const f32x4 ai[3], const f32x4 ah[3], float c2[4], const int q, const int j)
{
  #pragma unroll
  for (int r = 0; r < 4; ++r) {
    const int m = q * 4 + r;
    const int off = FOFF(m, j);
    float rg = 1.f / (1.f + expf(-(ai[0][r] + ah[0][r])));
    float zg = 1.f / (1.f + expf(-(ai[1][r] + ah[1][r])));
    float ng = tanhf(ai[2][r] + rg * ah[2][r]);
    float hp = (float)hc0[off] + (float)hc1[off] + c2[r];
    float hv = (1.f - zg) * ng + zg * hp;
    bf16 d0 = (bf16)hv;  float r1 = hv - (float)d0;
    bf16 d1 = (bf16)r1;  c2[r] = r1 - (float)d1;
    hc0[off] = d0;
    hc1[off] = d1;
  }
}

__global__ __launch_bounds__(1024, 4)
void moldec_mfma(const float* __restrict__ z, const float* __restrict__ emb,
                 const float* __restrict__ z2h_b, const float* __restrict__ out_b,
                 const float* __restrict__ bih0, const float* __restrict__ bhh0,
                 const float* __restrict__ bih1, const float* __restrict__ bhh1,
                 const float* __restrict__ bih2, const float* __restrict__ bhh2,
                 const bf16* __restrict__ wsb, int* __restrict__ ws_i,
                 float* __restrict__ out)
{
  __shared__ __align__(16) bf16 hS[3][2][4096];   // [layer][comp][kt*512] frag-major
  __shared__ __align__(16) bf16 xzS[2][4][512];   // x (kt 0-1) / z-init (kt 0-3)
  __shared__ float logS2[2][16][66];

  const int tid  = threadIdx.x;
  const int wave = tid >> 6;
  const int lane = tid & 63;
  const int q    = lane >> 4;
  const int r15  = lane & 15;
  const int b0   = blockIdx.x * BM;
  const int j    = wave * 16 + r15;   // neuron owned by this thread (per layer)

  // hoisted per-thread biases [layer][gate] at col j
  float bi_[3][3], bh_[3][3];
  #pragma unroll
  for (int g = 0; g < 3; ++g) {
    bi_[0][g] = bih0[g * 256 + j];  bh_[0][g] = bhh0[g * 256 + j];
    bi_[1][g] = bih1[g * 256 + j];  bh_[1][g] = bhh1[g * 256 + j];
    bi_[2][g] = bih2[g * 256 + j];  bh_[2][g] = bhh2[g * 256 + j];
  }
  float c2_0[4], c2_1[4], c2_2[4];   // h comp2 per layer, rows m=q*4+r

  // ---- stage z into frag layout (2 comps) ----
  if (tid < 512) {
    const int m = tid >> 5, c4 = (tid & 31) * 4;
    float4 v = *(const float4*)(z + (size_t)(b0 + m) * 128 + c4);
    const float vv[4] = {v.x, v.y, v.z, v.w};
    #pragma unroll
    for (int e = 0; e < 4; ++e) {
      const int off = FOFF(m, c4 + e);
      bf16 hi = (bf16)vv[e];
      (&xzS[0][0][0])[off] = hi;
      (&xzS[1][0][0])[off] = (bf16)(vv[e] - (float)hi);
    }
  }
  __syncthreads();

  // ---- h0 = tanh(z @ z2h_w.T + b) ----
  {
    f32x4 acc[3];
    #pragma unroll
    for (int t = 0; t < 3; ++t) acc[t] = splat4(z2h_b[t * 256 + j]);
    gemm3f<4, 3>(acc, &xzS[0][0][0], &xzS[1][0][0], wsb + O_Z2H, wave, 16, lane);
    #pragma unroll
    for (int t = 0; t < 3; ++t) {
      float* c2p = t == 0 ? c2_0 : (t == 1 ? c2_1 : c2_2);
      #pragma unroll
      for (int r = 0; r < 4; ++r) {
        const int m = q * 4 + r;
        const int off = FOFF(m, j);
        float hv = tanhf(acc[t][r]);
        bf16 d0 = (bf16)hv;  float r1 = hv - (float)d0;
        bf16 d1 = (bf16)r1;  c2p[r] = r1 - (float)d1;
        hS[t][0][off] = d0;
        hS[t][1][off] = d1;
      }
    }
  }
  __syncthreads();

  // ---- stage x = emb[1] (wave w = batch row w, lane = elem) ----
  {
    float ev = emb[64 + lane];
    const int off = FOFF(wave, lane);
    bf16 hi = (bf16)ev;
    (&xzS[0][0][0])[off] = hi;
    (&xzS[1][0][0])[off] = (bf16)(ev - (float)hi);
  }

  for (int step = 0; step < NSTEP; ++step) {
    const int ep0 = step * 4;
    f32x4 ai[3], ah[3];

    // ---- B0: ai0 = wih0 @ x  (196 KB phase) ----
    phase_bar(ws_i, ep0 + 1);
    #pragma unroll
    for (int t = 0; t < 3; ++t) ai[t] = splat4(bi_[0][t]);
    gemm3f<2, 3>(ai, &xzS[0][0][0], &xzS[1][0][0], wsb + O_WIH0, wave, 16, lane);

    // ---- B1: whh0 @ h0 ; upd h0 ; wih1 @ h0'  (1.57 MB phase) ----
    phase_bar(ws_i, ep0 + 2);
    #pragma unroll
    for (int t = 0; t < 3; ++t) ah[t] = splat4(bh_[0][t]);
    gemm3f<8, 3>(ah, hS[0][0], hS[0][1], wsb + O_WHH0, wave, 16, lane);
    __syncthreads();
    upd(hS[0][0], hS[0][1], ai, ah, c2_0, q, j);
    __syncthreads();
    #pragma unroll
    for (int t = 0; t < 3; ++t) ai[t] = splat4(bi_[1][t]);
    gemm3f<8, 3>(ai, hS[0][0], hS[0][1], wsb + O_WIH1, wave, 16, lane);

    // ---- B2: whh1 @ h1 ; upd h1 ; wih2 @ h1'  (1.57 MB phase) ----
    phase_bar(ws_i, ep0 + 3);
    #pragma unroll
    for (int t = 0; t < 3; ++t) ah[t] = splat4(bh_[1][t]);
    gemm3f<8, 3>(ah, hS[1][0], hS[1][1], wsb + O_WHH1, wave, 16, lane);
    __syncthreads();
    upd(hS[1][0], hS[1][1], ai, ah, c2_1, q, j);
    __syncthreads();
    #pragma unroll
    for (int t = 0; t < 3; ++t) ai[t] = splat4(bi_[2][t]);
    gemm3f<8, 3>(ai, hS[1][0], hS[1][1], wsb + O_WIH2, wave, 16, lane);

    // ---- B3: whh2 @ h2 ; upd h2 ; logits ; argmax ; stage x'  (851 KB phase) ----
    phase_bar(ws_i, ep0 + 4);
    #pragma unroll
    for (int t = 0; t < 3; ++t) ah[t] = splat4(bh_[2][t]);
    gemm3f<8, 3>(ah, hS[2][0], hS[2][1], wsb + O_WHH2, wave, 16, lane);
    __syncthreads();
    upd(hS[2][0], hS[2][1], ai, ah, c2_2, q, j);
    __syncthreads();

    if (wave < 8) {
      const int tt = wave >> 1, kh = wave & 1;
      f32x4 acc = (kh == 0) ? splat4(out_b[tt * 16 + r15]) : splat4(0.f);
      gemm3f<4, 1>(&acc, hS[2][0] + kh * 2048, hS[2][1] + kh * 2048,
                   wsb + O_OUTW + (size_t)(tt * 8 + kh * 4) * 1024, 0, 0, lane);
      #pragma unroll
      for (int r = 0; r < 4; ++r)
        logS2[kh][q * 4 + r][tt * 16 + r15] = acc[r];
    }
    __syncthreads();

    {
      float v = logS2[0][wave][lane] + logS2[1][wave][lane];
      out[((size_t)(b0 + wave) * NSTEP + step) * 64 + lane] = v;
      float bv = v;
      int   bi = lane;
      #pragma unroll
      for (int d = 1; d < 64; d <<= 1) {
        float ov = __shfl_xor(bv, d);
        int   oi = __shfl_xor(bi, d);
        if (ov > bv || (ov == bv && oi < bi)) { bv = ov; bi = oi; }
      }
      float ev = emb[(size_t)bi * 64 + lane];
      const int off = FOFF(wave, lane);
      bf16 hi = (bf16)ev;
      (&xzS[0][0][0])[off] = hi;
      (&xzS[1][0][0])[off] = (bf16)(ev - (float)hi);
    }
    __syncthreads();
  }
}

extern "C" void kernel_launch(void* const* d_in, const int* in_sizes, int n_in,
                              void* d_out, int out_size, void* d_ws, size_t ws_size,
                              hipStream_t stream) {
  bf16* wsb = (bf16*)d_ws;
  int*  wsi = (int*)d_ws;

  bar_init<<<1, 256, 0, stream>>>(wsi);

  pack2<<<48, 256, 0, stream>>>((const float*)d_in[2],  wsb + O_Z2H,  48, 4);
  pack2<<<24, 256, 0, stream>>>((const float*)d_in[6],  wsb + O_WIH0, 48, 2);
  pack2<<<96, 256, 0, stream>>>((const float*)d_in[7],  wsb + O_WHH0, 48, 8);
  pack2<<<96, 256, 0, stream>>>((const float*)d_in[10], wsb + O_WIH1, 48, 8);
  pack2<<<96, 256, 0, stream>>>((const float*)d_in[11], wsb + O_WHH1, 48, 8);
  pack2<<<96, 256, 0, stream>>>((const float*)d_in[14], wsb + O_WIH2, 48, 8);
  pack2<<<96, 256, 0, stream>>>((const float*)d_in[15], wsb + O_WHH2, 48, 8);
  pack2<<<8,  256, 0, stream>>>((const float*)d_in[4],  wsb + O_OUTW, 4,  8);

  moldec_mfma<<<NBLK, 1024, 0, stream>>>(
      (const float*)d_in[0],  (const float*)d_in[1],
      (const float*)d_in[3],  (const float*)d_in[5],
      (const float*)d_in[8],  (const float*)d_in[9],
      (const float*)d_in[12], (const float*)d_in[13],
      (const float*)d_in[16], (const float*)d_in[17],
      wsb, wsi, (float*)d_out);
}

// Round 10
// 23147.194 us; speedup vs baseline: 1.2629x; 1.2629x over previous
//
#include <hip/hip_runtime.h>
#include <hip/hip_bf16.h>

typedef __bf16 bf16;
typedef __bf16 bf16x8 __attribute__((ext_vector_type(8)));
typedef float  f32x4  __attribute__((ext_vector_type(4)));

#define MFMA16(a,b,c) __builtin_amdgcn_mfma_f32_16x16x32_bf16((a),(b),(c),0,0,0)
#define NSTEP 119
#define BM 16
#define NBLK 256
#define GRP 32

// ws offsets (bf16 elements); frag block (c,kt) = 1024 bf16: [hi 512][lo 512]
#define O_Z2H   0u
#define O_WIH0  196608u
#define O_WHH0  294912u
#define O_WIH1  688128u
#define O_WHH1  1081344u
#define O_WIH2  1474560u
#define O_WHH2  1867776u
#define O_OUTW  2260992u
// barrier words (int indices): after O_OUTW + 32768 bf16 = int index 1146880
#define IBAR_SUB(g) (1146880 + 16 * (g))
#define IBAR_MST    (1146880 + 128)

// A-fragment-major offset for element (row m, col k): lane = m+16*((k>>3)&3), elem k&7
#define FOFF(m,k) (((k)>>5)*512 + ((m) + 16*(((k)>>3)&3))*8 + ((k)&7))

__device__ __forceinline__ f32x4 splat4(float v){ f32x4 r={v,v,v,v}; return r; }

__global__ void bar_init(int* ws_i) {
  int i = threadIdx.x;
  if (i < 160) ws_i[1146880 + i] = 0;
}

// fp32 W[Rt*16][KT*32] row-major -> MFMA B-fragments, hi/lo bf16 split.
__global__ void pack2(const float* __restrict__ src, bf16* __restrict__ dst,
                      int Rt, int KT) {
  int idx = blockIdx.x * 256 + threadIdx.x;
  if (idx >= Rt * KT * 64) return;
  int lane = idx & 63, fi = idx >> 6;
  int r15 = lane & 15, q = lane >> 4;
  int c = fi / KT, kt = fi - c * KT;
  const float* s = src + (size_t)(c * 16 + r15) * (KT * 32) + kt * 32 + q * 8;
  bf16* dhi = dst + (size_t)fi * 1024 + lane * 8;
  bf16* dlo = dhi + 512;
  #pragma unroll
  for (int e = 0; e < 8; ++e) {
    float v = s[e];
    bf16 hi = (bf16)v;
    dhi[e] = hi;
    dlo[e] = (bf16)(v - (float)hi);
  }
}

// Phase barrier (unchanged from R9): arrivals two-level RMW, release = RELAXED
// AGENT load poll. Pure cache-phasing; timeout -> perf loss only, never hang.
__device__ __forceinline__ void phase_bar(int* __restrict__ wsi, int epoch) {
  __syncthreads();
  if (threadIdx.x == 0) {
    const int g = blockIdx.x & 7;
    int old = atomicAdd(wsi + IBAR_SUB(g), 1);
    if ((old & 0xffff) == GRP - 1) {
      int old2 = atomicAdd(wsi + IBAR_SUB(g), (1 << 16) - GRP);  // reset cnt, bump sub-sense
      int m = atomicAdd(wsi + IBAR_MST, 1 + (int)(old2 >> 31)); // dep on old2 => ordered
      if ((m & 0xffff) == 7)
        atomicAdd(wsi + IBAR_MST, (1 << 16) - 8);               // master sense += 1
    }
    for (int it = 0; it < 2000000; ++it) {
      int v = __hip_atomic_load(wsi + IBAR_MST, __ATOMIC_RELAXED,
                                __HIP_MEMORY_SCOPE_AGENT);
      if ((v >> 16) >= epoch) break;
      __builtin_amdgcn_s_sleep(2);
    }
  }
  __syncthreads();
}

// asm-pinned 16B global load (order preserved among volatile asm; no memory
// clobber needed: weights are read-only during the kernel).
__device__ __forceinline__ void gl16(bf16x8& d, const bf16* p) {
  asm volatile("global_load_dwordx4 %0, %1, off" : "=v"(d) : "v"(p));
}

// acc[NT] += A x W^T, 3-pass split MFMA. B-frags loaded through a 3-deep
// asm-pinned register ring with counted vmcnt waits (T4 pattern):
// prologue issues slices 0,1; iter kt issues kt+2, waits vmcnt(4NT/2NT/0),
// sched_barrier(0) (rule #18), then consumes slice kt. Entry drains vmcnt(0)
// so earlier stores/gathers can't skew the counts.
template<int KT, int NT>
__device__ __forceinline__ void gemm3p(f32x4* acc,
    const bf16* __restrict__ A0, const bf16* __restrict__ A1,
    const bf16* __restrict__ BF, const int cbase, const int cstep, const int lane)
{
  const bf16* bp[NT];
  #pragma unroll
  for (int t = 0; t < NT; ++t)
    bp[t] = BF + (size_t)(cbase + t * cstep) * KT * 1024 + lane * 8;

  bf16x8 rb[3][NT][2];
  asm volatile("s_waitcnt vmcnt(0)" ::: "memory");
  __builtin_amdgcn_sched_barrier(0);
  #pragma unroll
  for (int p = 0; p < 2; ++p) {
    if (p < KT) {
      #pragma unroll
      for (int t = 0; t < NT; ++t) {
        gl16(rb[p][t][0], bp[t] + p * 1024);
        gl16(rb[p][t][1], bp[t] + p * 1024 + 512);
      }
    }
  }
  #pragma unroll
  for (int kt = 0; kt < KT; ++kt) {
    if (kt + 2 < KT) {
      #pragma unroll
      for (int t = 0; t < NT; ++t) {
        gl16(rb[(kt + 2) % 3][t][0], bp[t] + (kt + 2) * 1024);
        gl16(rb[(kt + 2) % 3][t][1], bp[t] + (kt + 2) * 1024 + 512);
      }
    }
    const int rem = KT - 1 - kt;
    if (rem >= 2)      asm volatile("s_waitcnt vmcnt(%0)" :: "n"(4 * NT) : "memory");
    else if (rem == 1) asm volatile("s_waitcnt vmcnt(%0)" :: "n"(2 * NT) : "memory");
    else               asm volatile("s_waitcnt vmcnt(0)" ::: "memory");
    __builtin_amdgcn_sched_barrier(0);
    bf16x8 a0 = *(const bf16x8*)(A0 + kt * 512 + lane * 8);
    bf16x8 a1 = *(const bf16x8*)(A1 + kt * 512 + lane * 8);
    #pragma unroll
    for (int t = 0; t < NT; ++t) {
      acc[t] = MFMA16(a0, rb[kt % 3][t][0], acc[t]);
      acc[t] = MFMA16(a1, rb[kt % 3][t][0], acc[t]);
      acc[t] = MFMA16(a0, rb[kt % 3][t][1], acc[t]);
    }
  }
}

// GRU gate update for one layer; h comps 0/1 in LDS (frag-major), comp2 in regs.
__device__ __forceinline__ void upd(bf16* __restrict__ hc0, bf16* __restrict__ hc1,
    const f32x4 ai[3], const f32x4 ah[3], float c2[4], const int q, const int j)
{
  #pragma unroll
  for (int r = 0; r < 4; ++r) {
    const int m = q * 4 + r;
    const int off = FOFF(m, j);
    float rg = 1.f / (1.f + expf(-(ai[0][r] + ah[0][r])));
    float zg = 1.f / (1.f + expf(-(ai[1][r] + ah[1][r])));
    float ng = tanhf(ai[2][r] + rg * ah[2][r]);
    float hp = (float)hc0[off] + (float)hc1[off] + c2[r];
    float hv = (1.f - zg) * ng + zg * hp;
    bf16 d0 = (bf16)hv;  float r1 = hv - (float)d0;
    bf16 d1 = (bf16)r1;  c2[r] = r1 - (float)d1;
    hc0[off] = d0;
    hc1[off] = d1;
  }
}

__global__ __launch_bounds__(1024, 4)
void moldec_mfma(const float* __restrict__ z, const float* __restrict__ emb,
                 const float* __restrict__ z2h_b, const float* __restrict__ out_b,
                 const float* __restrict__ bih0, const float* __restrict__ bhh0,
                 const float* __restrict__ bih1, const float* __restrict__ bhh1,
                 const float* __restrict__ bih2, const float* __restrict__ bhh2,
                 const bf16* __restrict__ wsb, int* __restrict__ ws_i,
                 float* __restrict__ out)
{
  __shared__ __align__(16) bf16 hS[3][2][4096];   // [layer][comp][kt*512] frag-major
  __shared__ __align__(16) bf16 xzS[2][4][512];   // x (kt 0-1) / z-init (kt 0-3)
  __shared__ float logS2[2][16][66];

  const int tid  = threadIdx.x;
  const int wave = tid >> 6;
  const int lane = tid & 63;
  const int q    = lane >> 4;
  const int r15  = lane & 15;
  const int b0   = blockIdx.x * BM;
  const int j    = wave * 16 + r15;   // neuron owned by this thread (per layer)

  // hoisted per-thread biases [layer][gate] at col j
  float bi_[3][3], bh_[3][3];
  #pragma unroll
  for (int g = 0; g < 3; ++g) {
    bi_[0][g] = bih0[g * 256 + j];  bh_[0][g] = bhh0[g * 256 + j];
    bi_[1][g] = bih1[g * 256 + j];  bh_[1][g] = bhh1[g * 256 + j];
    bi_[2][g] = bih2[g * 256 + j];  bh_[2][g] = bhh2[g * 256 + j];
  }
  float c2_0[4], c2_1[4], c2_2[4];   // h comp2 per layer, rows m=q*4+r

  // ---- stage z into frag layout (2 comps) ----
  if (tid < 512) {
    const int m = tid >> 5, c4 = (tid & 31) * 4;
    float4 v = *(const float4*)(z + (size_t)(b0 + m) * 128 + c4);
    const float vv[4] = {v.x, v.y, v.z, v.w};
    #pragma unroll
    for (int e = 0; e < 4; ++e) {
      const int off = FOFF(m, c4 + e);
      bf16 hi = (bf16)vv[e];
      (&xzS[0][0][0])[off] = hi;
      (&xzS[1][0][0])[off] = (bf16)(vv[e] - (float)hi);
    }
  }
  __syncthreads();

  // ---- h0 = tanh(z @ z2h_w.T + b) ----
  {
    f32x4 acc[3];
    #pragma unroll
    for (int t = 0; t < 3; ++t) acc[t] = splat4(z2h_b[t * 256 + j]);
    gemm3p<4, 3>(acc, &xzS[0][0][0], &xzS[1][0][0], wsb + O_Z2H, wave, 16, lane);
    #pragma unroll
    for (int t = 0; t < 3; ++t) {
      float* c2p = t == 0 ? c2_0 : (t == 1 ? c2_1 : c2_2);
      #pragma unroll
      for (int r = 0; r < 4; ++r) {
        const int m = q * 4 + r;
        const int off = FOFF(m, j);
        float hv = tanhf(acc[t][r]);
        bf16 d0 = (bf16)hv;  float r1 = hv - (float)d0;
        bf16 d1 = (bf16)r1;  c2p[r] = r1 - (float)d1;
        hS[t][0][off] = d0;
        hS[t][1][off] = d1;
      }
    }
  }
  __syncthreads();

  // ---- stage x = emb[1] (wave w = batch row w, lane = elem) ----
  {
    float ev = emb[64 + lane];
    const int off = FOFF(wave, lane);
    bf16 hi = (bf16)ev;
    (&xzS[0][0][0])[off] = hi;
    (&xzS[1][0][0])[off] = (bf16)(ev - (float)hi);
  }

  for (int step = 0; step < NSTEP; ++step) {
    const int ep0 = step * 4;
    f32x4 ai[3], ah[3];

    // ---- B0: ai0 = wih0 @ x  (196 KB phase) ----
    phase_bar(ws_i, ep0 + 1);
    #pragma unroll
    for (int t = 0; t < 3; ++t) ai[t] = splat4(bi_[0][t]);
    gemm3p<2, 3>(ai, &xzS[0][0][0], &xzS[1][0][0], wsb + O_WIH0, wave, 16, lane);

    // ---- B1: whh0 @ h0 ; upd h0 ; wih1 @ h0'  (1.57 MB phase) ----
    phase_bar(ws_i, ep0 + 2);
    #pragma unroll
    for (int t = 0; t < 3; ++t) ah[t] = splat4(bh_[0][t]);
    gemm3p<8, 3>(ah, hS[0][0], hS[0][1], wsb + O_WHH0, wave, 16, lane);
    __syncthreads();
    upd(hS[0][0], hS[0][1], ai, ah, c2_0, q, j);
    __syncthreads();
    #pragma unroll
    for (int t = 0; t < 3; ++t) ai[t] = splat4(bi_[1][t]);
    gemm3p<8, 3>(ai, hS[0][0], hS[0][1], wsb + O_WIH1, wave, 16, lane);

    // ---- B2: whh1 @ h1 ; upd h1 ; wih2 @ h1'  (1.57 MB phase) ----
    phase_bar(ws_i, ep0 + 3);
    #pragma unroll
    for (int t = 0; t < 3; ++t) ah[t] = splat4(bh_[1][t]);
    gemm3p<8, 3>(ah, hS[1][0], hS[1][1], wsb + O_WHH1, wave, 16, lane);
    __syncthreads();
    upd(hS[1][0], hS[1][1], ai, ah, c2_1, q, j);
    __syncthreads();
    #pragma unroll
    for (int t = 0; t < 3; ++t) ai[t] = splat4(bi_[2][t]);
    gemm3p<8, 3>(ai, hS[1][0], hS[1][1], wsb + O_WIH2, wave, 16, lane);

    // ---- B3: whh2 @ h2 ; upd h2 ; logits ; argmax ; stage x'  (851 KB phase) ----
    phase_bar(ws_i, ep0 + 4);
    #pragma unroll
    for (int t = 0; t < 3; ++t) ah[t] = splat4(bh_[2][t]);
    gemm3p<8, 3>(ah, hS[2][0], hS[2][1], wsb + O_WHH2, wave, 16, lane);
    __syncthreads();
    upd(hS[2][0], hS[2][1], ai, ah, c2_2, q, j);
    __syncthreads();

    if (wave < 8) {
      const int tt = wave >> 1, kh = wave & 1;
      f32x4 acc = (kh == 0) ? splat4(out_b[tt * 16 + r15]) : splat4(0.f);
      gemm3p<4, 1>(&acc, hS[2][0] + kh * 2048, hS[2][1] + kh * 2048,
                   wsb + O_OUTW + (size_t)(tt * 8 + kh * 4) * 1024, 0, 0, lane);
      #pragma unroll
      for (int r = 0; r < 4; ++r)
        logS2[kh][q * 4 + r][tt * 16 + r15] = acc[r];
    }
    __syncthreads();

    {
      float v = logS2[0][wave][lane] + logS2[1][wave][lane];
      out[((size_t)(b0 + wave) * NSTEP + step) * 64 + lane] = v;
      float bv = v;
      int   bi = lane;
      #pragma unroll
      for (int d = 1; d < 64; d <<= 1) {
        float ov = __shfl_xor(bv, d);
        int   oi = __shfl_xor(bi, d);
        if (ov > bv || (ov == bv && oi < bi)) { bv = ov; bi = oi; }
      }
      float ev = emb[(size_t)bi * 64 + lane];
      const int off = FOFF(wave, lane);
      bf16 hi = (bf16)ev;
      (&xzS[0][0][0])[off] = hi;
      (&xzS[1][0][0])[off] = (bf16)(ev - (float)hi);
    }
    __syncthreads();
  }
}

extern "C" void kernel_launch(void* const* d_in, const int* in_sizes, int n_in,
                              void* d_out, int out_size, void* d_ws, size_t ws_size,
                              hipStream_t stream) {
  bf16* wsb = (bf16*)d_ws;
  int*  wsi = (int*)d_ws;

  bar_init<<<1, 256, 0, stream>>>(wsi);

  pack2<<<48, 256, 0, stream>>>((const float*)d_in[2],  wsb + O_Z2H,  48, 4);
  pack2<<<24, 256, 0, stream>>>((const float*)d_in[6],  wsb + O_WIH0, 48, 2);
  pack2<<<96, 256, 0, stream>>>((const float*)d_in[7],  wsb + O_WHH0, 48, 8);
  pack2<<<96, 256, 0, stream>>>((const float*)d_in[10], wsb + O_WIH1, 48, 8);
  pack2<<<96, 256, 0, stream>>>((const float*)d_in[11], wsb + O_WHH1, 48, 8);
  pack2<<<96, 256, 0, stream>>>((const float*)d_in[14], wsb + O_WIH2, 48, 8);
  pack2<<<96, 256, 0, stream>>>((const float*)d_in[15], wsb + O_WHH2, 48, 8);
  pack2<<<8,  256, 0, stream>>>((const float*)d_in[4],  wsb + O_OUTW, 4,  8);

  moldec_mfma<<<NBLK, 1024, 0, stream>>>(
      (const float*)d_in[0],  (const float*)d_in[1],
      (const float*)d_in[3],  (const float*)d_in[5],
      (const float*)d_in[8],  (const float*)d_in[9],
      (const float*)d_in[12], (const float*)d_in[13],
      (const float*)d_in[16], (const float*)d_in[17],
      wsb, wsi, (float*)d_out);
}

// Round 11
// 19216.534 us; speedup vs baseline: 1.5212x; 1.2045x over previous
//
#include <hip/hip_runtime.h>
#include <hip/hip_bf16.h>

typedef __bf16 bf16;
typedef __bf16 bf16x8 __attribute__((ext_vector_type(8)));
typedef float  f32x4  __attribute__((ext_vector_type(4)));

#define MFMA16(a,b,c) __builtin_amdgcn_mfma_f32_16x16x32_bf16((a),(b),(c),0,0,0)
#define NSTEP 119
#define BM 32
#define NBLK 128

// ws offsets (bf16 elems). Fused-K groups; frag (c,kt) = 1024 bf16 [hi512|lo512].
#define O_L0   0u         // 48 tiles x KTg=10 (kt0-1 wih0, kt2-9 whh0)
#define O_L1   491520u    // 48 x 16 (kt0-7 wih1, kt8-15 whh1)
#define O_L2   1277952u   // 48 x 16
#define O_Z2H  2064384u   // 48 x 4
#define O_OUTW 2260992u   // 4 x 8

// A-frag offset for (row m in 0..15, col k): lane = m+16*((k>>3)&3), elem k&7
#define FOFF(m,k) (((k)>>5)*512 + ((m) + 16*(((k)>>3)&3))*8 + ((k)&7))

__device__ __forceinline__ f32x4 splat4(float v){ f32x4 r={v,v,v,v}; return r; }

__device__ __forceinline__ unsigned pk2(float a, float b){
  union { __bf16 h[2]; unsigned u; } x;
  x.h[0] = (bf16)a; x.h[1] = (bf16)b; return x.u;
}
__device__ __forceinline__ float upk(unsigned u, int i){
  union { __bf16 h[2]; unsigned u; } x;
  x.u = u; return (float)x.h[i];
}
__device__ __forceinline__ float sigf(float x){ return 1.f/(1.f+expf(-x)); }

// fp32 W[Rt*16][K] -> fused-group MFMA B-frags, hi/lo split.
// dst frag index = c*KTg + ktoff + ktm.
__global__ void pack2(const float* __restrict__ src, bf16* __restrict__ dst,
                      int Rt, int KTm, int KTg, int ktoff, int K) {
  int idx = blockIdx.x * 256 + threadIdx.x;
  if (idx >= Rt * KTm * 64) return;
  int lane = idx & 63, fi = idx >> 6;
  int r15 = lane & 15, q = lane >> 4;
  int c = fi / KTm, ktm = fi - c * KTm;
  const float* s = src + (size_t)(c * 16 + r15) * K + ktm * 32 + q * 8;
  bf16* d = dst + (size_t)(c * KTg + ktoff + ktm) * 1024 + lane * 8;
  #pragma unroll
  for (int e = 0; e < 8; ++e) {
    float v = s[e];
    bf16 hi = (bf16)v;
    d[e] = hi;
    d[e + 512] = (bf16)(v - (float)hi);
  }
}

// asm-pinned 16B load (volatile order preserved vs the waitcnt asms).
__device__ __forceinline__ void gl16(bf16x8& d, const bf16* p) {
  asm volatile("global_load_dwordx4 %0, %1, off" : "=v"(d) : "v"(p));
}

// Fused-K GEMM: gates += [Ai (kt<KTI) | Ah (kt>=KTI)] @ Wfused^T.
// r,z tiles accumulate into aRZ; n-tile routes to aI (input part) / aH (h part).
// Ring-2 B-prefetch, counted vmcnt(6), sched_barrier after waits (rule #18).
template<int KTI, int KT, int KTG>
__device__ __forceinline__ void gemmF(
    f32x4 (&aRZ)[2][2], f32x4 (&aI)[2], f32x4 (&aH)[2],
    const bf16* __restrict__ Ai0, const bf16* __restrict__ Ai1, const int SAI,
    const bf16* __restrict__ Ah0, const bf16* __restrict__ Ah1, const int SAH,
    const bf16* __restrict__ BG, const int wv, const int lane)
{
  const size_t TS = (size_t)16 * KTG * 1024;   // col-tile stride (16 tiles apart)
  const bf16* bp = BG + (size_t)wv * KTG * 1024 + lane * 8;
  bf16x8 rb[2][3][2];
  asm volatile("s_waitcnt vmcnt(0)" ::: "memory");   // drain stray vmem ops
  __builtin_amdgcn_sched_barrier(0);
  #pragma unroll
  for (int t = 0; t < 3; ++t) {
    gl16(rb[0][t][0], bp + t * TS);
    gl16(rb[0][t][1], bp + t * TS + 512);
  }
  #pragma unroll
  for (int kt = 0; kt < KT; ++kt) {
    const int s = kt & 1;
    if (kt + 1 < KT) {
      #pragma unroll
      for (int t = 0; t < 3; ++t) {
        gl16(rb[s ^ 1][t][0], bp + t * TS + (size_t)(kt + 1) * 1024);
        gl16(rb[s ^ 1][t][1], bp + t * TS + (size_t)(kt + 1) * 1024 + 512);
      }
      asm volatile("s_waitcnt vmcnt(6)" ::: "memory");
    } else {
      asm volatile("s_waitcnt vmcnt(0)" ::: "memory");
    }
    __builtin_amdgcn_sched_barrier(0);
    const bf16* A0 = (kt < KTI) ? Ai0 : Ah0;
    const bf16* A1 = (kt < KTI) ? Ai1 : Ah1;
    const int SA   = (kt < KTI) ? SAI : SAH;
    const int ka   = (kt < KTI) ? kt : (kt - KTI);
    #pragma unroll
    for (int rt = 0; rt < 2; ++rt) {
      bf16x8 a0 = *(const bf16x8*)(A0 + rt * SA + ka * 512 + lane * 8);
      bf16x8 a1 = *(const bf16x8*)(A1 + rt * SA + ka * 512 + lane * 8);
      aRZ[rt][0] = MFMA16(a0, rb[s][0][0], aRZ[rt][0]);
      aRZ[rt][0] = MFMA16(a1, rb[s][0][0], aRZ[rt][0]);
      aRZ[rt][0] = MFMA16(a0, rb[s][0][1], aRZ[rt][0]);
      aRZ[rt][1] = MFMA16(a0, rb[s][1][0], aRZ[rt][1]);
      aRZ[rt][1] = MFMA16(a1, rb[s][1][0], aRZ[rt][1]);
      aRZ[rt][1] = MFMA16(a0, rb[s][1][1], aRZ[rt][1]);
      f32x4& an = (kt < KTI) ? aI[rt] : aH[rt];
      an = MFMA16(a0, rb[s][2][0], an);
      an = MFMA16(a1, rb[s][2][0], an);
      an = MFMA16(a0, rb[s][2][1], an);
    }
  }
}

// GRU update; h comps 0/1 in LDS (frag-major), comp2 packed bf16-pairs in regs.
__device__ __forceinline__ void updF(
    bf16* __restrict__ h0, bf16* __restrict__ h1,
    const f32x4 (&aRZ)[2][2], const f32x4 (&aI)[2], const f32x4 (&aH)[2],
    unsigned (&c2p)[2][2], const int q, const int j)
{
  #pragma unroll
  for (int rt = 0; rt < 2; ++rt) {
    float c2v[4] = { upk(c2p[rt][0],0), upk(c2p[rt][0],1),
                     upk(c2p[rt][1],0), upk(c2p[rt][1],1) };
    #pragma unroll
    for (int r = 0; r < 4; ++r) {
      const int off = rt * 4096 + FOFF(q*4+r, j);
      float rg = sigf(aRZ[rt][0][r]);
      float zg = sigf(aRZ[rt][1][r]);
      float ng = tanhf(aI[rt][r] + rg * aH[rt][r]);
      float hp = (float)h0[off] + (float)h1[off] + c2v[r];
      float hv = (1.f - zg) * ng + zg * hp;
      bf16 d0 = (bf16)hv; float r1 = hv - (float)d0;
      bf16 d1 = (bf16)r1; c2v[r] = r1 - (float)d1;
      h0[off] = d0; h1[off] = d1;
    }
    c2p[rt][0] = pk2(c2v[0], c2v[1]);
    c2p[rt][1] = pk2(c2v[2], c2v[3]);
  }
}

__device__ __forceinline__ void setbias(const float* __restrict__ bSl, int j,
    f32x4 (&aRZ)[2][2], f32x4 (&aI)[2], f32x4 (&aH)[2]) {
  float br  = bSl[j] + bSl[768 + j];
  float bz  = bSl[256 + j] + bSl[768 + 256 + j];
  float bni = bSl[512 + j];
  float bnh = bSl[768 + 512 + j];
  #pragma unroll
  for (int rt = 0; rt < 2; ++rt) {
    aRZ[rt][0] = splat4(br); aRZ[rt][1] = splat4(bz);
    aI[rt] = splat4(bni);    aH[rt] = splat4(bnh);
  }
}

__global__ __launch_bounds__(1024)
void moldec_mfma(const float* __restrict__ z, const float* __restrict__ emb,
                 const float* __restrict__ z2h_b, const float* __restrict__ out_b,
                 const float* __restrict__ bih0, const float* __restrict__ bhh0,
                 const float* __restrict__ bih1, const float* __restrict__ bhh1,
                 const float* __restrict__ bih2, const float* __restrict__ bhh2,
                 const bf16* __restrict__ wsb, float* __restrict__ out)
{
  __shared__ __align__(16) bf16 hS[3][2][2][4096];  // [layer][comp][rt][8kt*512]
  __shared__ __align__(16) bf16 xzS[2][2][2048];    // [comp][rt][4kt*512]
  __shared__ float logS2[2][32][66];
  __shared__ float bS[3 * 1536];                    // [l][ih/hh][768]
  __shared__ float obS[64];

  const int tid = threadIdx.x, wave = tid >> 6, lane = tid & 63;
  const int q = lane >> 4, r15 = lane & 15;
  const int b0 = blockIdx.x * BM;
  const int wv = wave;
  const int j = wv * 16 + r15;       // owned neuron col (per layer)

  // ---- biases -> LDS ----
  {
    const float* bp_[6] = {bih0, bhh0, bih1, bhh1, bih2, bhh2};
    for (int i = tid; i < 4608; i += 1024) {
      int l = i / 1536, w2 = (i % 1536) / 768, g = i % 768;
      bS[i] = bp_[l * 2 + w2][g];
    }
    if (tid < 64) obS[tid] = out_b[tid];
  }

  // ---- stage z (32 rows x 128) into 2-comp frags ----
  {
    const int m = tid >> 5, c4 = (tid & 31) * 4;
    const int rt = m >> 4, mm = m & 15;
    float4 v = *(const float4*)(z + (size_t)(b0 + m) * 128 + c4);
    const float vv[4] = {v.x, v.y, v.z, v.w};
    #pragma unroll
    for (int e = 0; e < 4; ++e) {
      int off = FOFF(mm, c4 + e);
      bf16 hi = (bf16)vv[e];
      xzS[0][rt][off] = hi;
      xzS[1][rt][off] = (bf16)(vv[e] - (float)hi);
    }
  }
  __syncthreads();

  unsigned c2p[3][2][2];   // h comp2, packed bf16 pairs [layer][rt][rowpair]

  // ---- h0 = tanh(z @ z2h_w.T + b) ----
  {
    f32x4 acc[2][3];
    #pragma unroll
    for (int rt = 0; rt < 2; ++rt)
      #pragma unroll
      for (int t = 0; t < 3; ++t) acc[rt][t] = splat4(z2h_b[t * 256 + j]);
    #pragma unroll
    for (int kt = 0; kt < 4; ++kt) {
      #pragma unroll
      for (int rt = 0; rt < 2; ++rt) {
        bf16x8 a0 = *(const bf16x8*)(&xzS[0][rt][kt * 512 + lane * 8]);
        bf16x8 a1 = *(const bf16x8*)(&xzS[1][rt][kt * 512 + lane * 8]);
        #pragma unroll
        for (int t = 0; t < 3; ++t) {
          const bf16* bb = wsb + O_Z2H + (size_t)((wv + t * 16) * 4 + kt) * 1024 + lane * 8;
          bf16x8 b0 = *(const bf16x8*)bb;
          bf16x8 b1 = *(const bf16x8*)(bb + 512);
          acc[rt][t] = MFMA16(a0, b0, acc[rt][t]);
          acc[rt][t] = MFMA16(a1, b0, acc[rt][t]);
          acc[rt][t] = MFMA16(a0, b1, acc[rt][t]);
        }
      }
    }
    #pragma unroll
    for (int t = 0; t < 3; ++t)
      #pragma unroll
      for (int rt = 0; rt < 2; ++rt) {
        float c2v[4];
        #pragma unroll
        for (int r = 0; r < 4; ++r) {
          int off = rt * 4096 + FOFF(q * 4 + r, j);
          float hv = tanhf(acc[rt][t][r]);
          bf16 d0 = (bf16)hv; float r1 = hv - (float)d0;
          bf16 d1 = (bf16)r1; c2v[r] = r1 - (float)d1;
          (&hS[t][0][0][0])[off] = d0;
          (&hS[t][1][0][0])[off] = d1;
        }
        c2p[t][rt][0] = pk2(c2v[0], c2v[1]);
        c2p[t][rt][1] = pk2(c2v[2], c2v[3]);
      }
  }
  // ---- stage x = emb[1] for rows 2w, 2w+1 ----
  {
    float ev = emb[64 + lane];
    bf16 hi = (bf16)ev;
    bf16 lo = (bf16)(ev - (float)hi);
    #pragma unroll
    for (int k2 = 0; k2 < 2; ++k2) {
      int rr = wave * 2 + k2;
      int rt = rr >> 4, mm = rr & 15, off = FOFF(mm, lane);
      xzS[0][rt][off] = hi;
      xzS[1][rt][off] = lo;
    }
  }
  __syncthreads();

  for (int step = 0; step < NSTEP; ++step) {
    f32x4 aRZ[2][2], aI[2], aH[2];

    // ---- P0: layer 0, fused [x | h0] (KT = 2+8) ----
    setbias(bS, j, aRZ, aI, aH);
    gemmF<2, 10, 10>(aRZ, aI, aH,
                     &xzS[0][0][0], &xzS[1][0][0], 2048,
                     &hS[0][0][0][0], &hS[0][1][0][0], 4096,
                     wsb + O_L0, wv, lane);
    __syncthreads();
    updF(&hS[0][0][0][0], &hS[0][1][0][0], aRZ, aI, aH, c2p[0], q, j);
    __syncthreads();

    // ---- P1: layer 1, fused [h0' | h1] (KT = 8+8) ----
    setbias(bS + 1536, j, aRZ, aI, aH);
    gemmF<8, 16, 16>(aRZ, aI, aH,
                     &hS[0][0][0][0], &hS[0][1][0][0], 4096,
                     &hS[1][0][0][0], &hS[1][1][0][0], 4096,
                     wsb + O_L1, wv, lane);
    __syncthreads();
    updF(&hS[1][0][0][0], &hS[1][1][0][0], aRZ, aI, aH, c2p[1], q, j);
    __syncthreads();

    // ---- P2: layer 2, fused [h1' | h2] ----
    setbias(bS + 3072, j, aRZ, aI, aH);
    gemmF<8, 16, 16>(aRZ, aI, aH,
                     &hS[1][0][0][0], &hS[1][1][0][0], 4096,
                     &hS[2][0][0][0], &hS[2][1][0][0], 4096,
                     wsb + O_L2, wv, lane);
    __syncthreads();
    updF(&hS[2][0][0][0], &hS[2][1][0][0], aRZ, aI, aH, c2p[2], q, j);
    __syncthreads();

    // ---- logits: wave = (rt, tt, kh) 2x4x2 ----
    {
      const int rt = wave >> 3, tt = (wave >> 1) & 3, kh = wave & 1;
      f32x4 acc = kh ? splat4(0.f) : splat4(obS[tt * 16 + r15]);
      #pragma unroll
      for (int kt = 0; kt < 4; ++kt) {
        int kg = kh * 4 + kt;
        bf16x8 a0 = *(const bf16x8*)(&hS[2][0][rt][kg * 512 + lane * 8]);
        bf16x8 a1 = *(const bf16x8*)(&hS[2][1][rt][kg * 512 + lane * 8]);
        const bf16* bb = wsb + O_OUTW + (size_t)(tt * 8 + kg) * 1024 + lane * 8;
        bf16x8 b0 = *(const bf16x8*)bb;
        bf16x8 b1 = *(const bf16x8*)(bb + 512);
        acc = MFMA16(a0, b0, acc);
        acc = MFMA16(a1, b0, acc);
        acc = MFMA16(a0, b1, acc);
      }
      #pragma unroll
      for (int r = 0; r < 4; ++r)
        logS2[kh][rt * 16 + q * 4 + r][tt * 16 + r15] = acc[r];
    }
    __syncthreads();

    // ---- store + argmax (first-max) + stage next x; wave owns rows 2w,2w+1 ----
    #pragma unroll
    for (int k2 = 0; k2 < 2; ++k2) {
      int rr = wave * 2 + k2;
      float v = logS2[0][rr][lane] + logS2[1][rr][lane];
      out[((size_t)(b0 + rr) * NSTEP + step) * 64 + lane] = v;
      float bv = v; int bi = lane;
      #pragma unroll
      for (int d = 1; d < 64; d <<= 1) {
        float ov = __shfl_xor(bv, d);
        int   oi = __shfl_xor(bi, d);
        if (ov > bv || (ov == bv && oi < bi)) { bv = ov; bi = oi; }
      }
      float ev = emb[(size_t)bi * 64 + lane];
      int rt = rr >> 4, mm = rr & 15, off = FOFF(mm, lane);
      bf16 hi = (bf16)ev;
      xzS[0][rt][off] = hi;
      xzS[1][rt][off] = (bf16)(ev - (float)hi);
    }
    __syncthreads();
  }
}

extern "C" void kernel_launch(void* const* d_in, const int* in_sizes, int n_in,
                              void* d_out, int out_size, void* d_ws, size_t ws_size,
                              hipStream_t stream) {
  bf16* wsb = (bf16*)d_ws;

  pack2<<<24, 256, 0, stream>>>((const float*)d_in[6],  wsb + O_L0,  48, 2, 10, 0, 64);
  pack2<<<96, 256, 0, stream>>>((const float*)d_in[7],  wsb + O_L0,  48, 8, 10, 2, 256);
  pack2<<<96, 256, 0, stream>>>((const float*)d_in[10], wsb + O_L1,  48, 8, 16, 0, 256);
  pack2<<<96, 256, 0, stream>>>((const float*)d_in[11], wsb + O_L1,  48, 8, 16, 8, 256);
  pack2<<<96, 256, 0, stream>>>((const float*)d_in[14], wsb + O_L2,  48, 8, 16, 0, 256);
  pack2<<<96, 256, 0, stream>>>((const float*)d_in[15], wsb + O_L2,  48, 8, 16, 8, 256);
  pack2<<<48, 256, 0, stream>>>((const float*)d_in[2],  wsb + O_Z2H, 48, 4, 4,  0, 128);
  pack2<<<8,  256, 0, stream>>>((const float*)d_in[4],  wsb + O_OUTW, 4, 8, 8,  0, 256);

  moldec_mfma<<<NBLK, 1024, 0, stream>>>(
      (const float*)d_in[0],  (const float*)d_in[1],
      (const float*)d_in[3],  (const float*)d_in[5],
      (const float*)d_in[8],  (const float*)d_in[9],
      (const float*)d_in[12], (const float*)d_in[13],
      (const float*)d_in[16], (const float*)d_in[17],
      wsb, (float*)d_out);
}